// Round 5
// baseline (20.548 us; speedup 1.0000x reference)
//
#include <hip/hip_runtime.h>
#include <hip/hip_bf16.h>

using frag_ab = __attribute__((ext_vector_type(8))) short;   // 8 bf16 in 4 VGPRs
using f32x4   = __attribute__((ext_vector_type(4))) float;
using i32x4   = __attribute__((ext_vector_type(4))) int;
using u32x4   = __attribute__((ext_vector_type(4))) unsigned int;
typedef float f32x4u __attribute__((ext_vector_type(4), aligned(4)));
using u16x8   = __attribute__((ext_vector_type(8))) unsigned short;  // 16 B

#if defined(__has_builtin)
#  if __has_builtin(__builtin_amdgcn_make_buffer_rsrc) && __has_builtin(__builtin_amdgcn_raw_buffer_load_b128)
#    define USE_BUF_SC0 1
#  endif
#endif

// ======== compile-time twiddle table ========
// B(320 x 80): col 0..34 = cos(2*pi*(7+j)*k/300), col 35..69 = sin(...), else 0.
// Packed in MFMA fragment order, one chunk per kc:
//   chunk[kc].v[(n*64 + lane)*8 + e],  k = kc*32 + (lane>>4)*8 + e, col = n*16 + (lane&15)

struct CS { double c[300]; double s[300]; };

constexpr CS make_cs() {
    CS t{};
    const double PI = 3.14159265358979323846;
    for (int m = 0; m < 300; ++m) {
        int q = m / 75, r = m % 75;
        double th = PI * (double)r / 150.0;     // [0, pi/2)
        double x2 = th * th;
        double term = 1.0, cv = 0.0;
        for (int k2 = 0; k2 < 12; ++k2) { cv += term; term *= -x2 / ((2*k2+1)*(2*k2+2)); }
        double sv = 0.0; term = th;
        for (int k2 = 0; k2 < 12; ++k2) { sv += term; term *= -x2 / ((2*k2+2)*(2*k2+3)); }
        double cc = 0.0, ss = 0.0;
        if      (q == 0) { cc =  cv; ss =  sv; }
        else if (q == 1) { cc = -sv; ss =  cv; }
        else if (q == 2) { cc = -cv; ss = -sv; }
        else             { cc =  sv; ss = -cv; }
        t.c[m] = cc; t.s[m] = ss;
    }
    return t;
}
constexpr CS TAB = make_cs();

constexpr unsigned short d2bf(double v) {
    unsigned s = 0; double a = v;
    if (a < 0) { s = 1; a = -a; }
    if (a < 1e-8) return 0;                 // exact zeros of the twiddle grid
    int e = 0;
    while (a >= 2.0) { a *= 0.5; ++e; }
    while (a <  1.0) { a *= 2.0; --e; }
    double m = (a - 1.0) * 128.0;           // 7-bit bf16 mantissa
    int mi = (int)(m + 0.5);
    int ef = 127 + e;
    if (mi == 128) { mi = 0; ++ef; }
    return (unsigned short)((s << 15) | ((unsigned)ef << 7) | (unsigned)mi);
}

struct alignas(16) Chunk { unsigned short v[2560]; };   // [n=5][lane=64][e=8]

constexpr Chunk make_chunk(int kc) {
    Chunk ch{};
    for (int i = 0; i < 2560; ++i) {
        int e = i & 7, l = (i >> 3) & 63, n = i >> 9;
        int k   = kc * 32 + ((l >> 4) << 3) + e;
        int col = n * 16 + (l & 15);
        double v = 0.0;
        if (k < 300 && col < 70) {
            int j = (col < 35) ? col : col - 35;
            int m = ((7 + j) * k) % 300;        // exact integer angle index
            v = (col < 35) ? TAB.c[m] : TAB.s[m];
        }
        ch.v[i] = d2bf(v);
    }
    return ch;
}

__device__ constexpr Chunk BPALL[10] = {
    make_chunk(0), make_chunk(1), make_chunk(2), make_chunk(3), make_chunk(4),
    make_chunk(5), make_chunk(6), make_chunk(7), make_chunk(8), make_chunk(9)
};

// 2 f32 -> packed 2x bf16 (low = lo, high = hi), single HW instruction
__device__ __forceinline__ unsigned cvtpk(float lo, float hi) {
    unsigned r;
    asm("v_cvt_pk_bf16_f32 %0, %1, %2" : "=v"(r) : "v"(lo), "v"(hi));
    return r;
}

// 512 threads = 8 waves, one (b,c) pair per wave.
// C(16x80) = A(16 windows x 320) * B(320 x 80), bf16 MFMA.
// B staged once to LDS; A gathered via sc0 buffer loads (L1-bypass) so the
// random-window gather rides L2's miss machinery, not the per-CU L1 MSHRs.
__global__ __launch_bounds__(512) void st_spec_main(
    const float* __restrict__ x, const int* __restrict__ offs,
    float* __restrict__ out)
{
    __shared__ __align__(16) unsigned short Bp[25600];   // 51200 B

    const int tid = threadIdx.x;

    // stage twiddle table: constexpr global -> LDS, 16 B per thread-iter
    {
        const u16x8* src = (const u16x8*)&BPALL[0];
        u16x8* dst = (u16x8*)Bp;
        #pragma unroll
        for (int i = 0; i < 6; ++i) dst[tid + i * 512] = src[tid + i * 512];
        int i6 = tid + 6 * 512;
        if (i6 < 3200) dst[i6] = src[i6];
    }

    const int wave = tid >> 6;
    const int lane = tid & 63;
    const int bc   = blockIdx.x * 8 + wave;     // 0..4095 (b*32+c)
    const int c16  = lane & 15;                 // A row = window index / C col
    const int kq   = lane >> 4;                 // k-quarter

    const int off = offs[bc * 16 + c16];
    const int base4 = (bc * 9000 + off) * 4;    // byte offset of window start (< 2^31)

#ifdef USE_BUF_SC0
    __amdgpu_buffer_rsrc_t rsrc = __builtin_amdgcn_make_buffer_rsrc(
        (void*)x, (short)0, 128 * 32 * 9000 * 4, 0x00020000);
#   define LOAD16(bo) __builtin_bit_cast(f32x4, __builtin_amdgcn_raw_buffer_load_b128(rsrc, (bo), 0, 1))
#else
#   define LOAD16(bo) (*(const f32x4u*)((const char*)x + (bo)))
#endif

    // A fragments straight from global (runtime offsets), zero-pad t>=300
    frag_ab a[10];
    #pragma unroll
    for (int kc = 0; kc < 9; ++kc) {           // t <= 295 < 300, safe
        int bo = base4 + (kc * 32 + kq * 8) * 4;
        f32x4 v0 = LOAD16(bo);
        f32x4 v1 = LOAD16(bo + 16);
        i32x4 w;
        w[0] = cvtpk(v0[0], v0[1]);
        w[1] = cvtpk(v0[2], v0[3]);
        w[2] = cvtpk(v1[0], v1[1]);
        w[3] = cvtpk(v1[2], v1[3]);
        a[kc] = __builtin_bit_cast(frag_ab, w);
    }
    {
        // tail k-chunk: kq=0 -> t 288..295 (all valid), kq=1 -> t 296..303
        // (296..299 valid), kq>=2 -> all >=300 -> zero
        i32x4 w = (i32x4){0, 0, 0, 0};
        if (kq == 0) {
            f32x4 v0 = LOAD16(base4 + 288 * 4);
            f32x4 v1 = LOAD16(base4 + 292 * 4);
            w[0] = cvtpk(v0[0], v0[1]);
            w[1] = cvtpk(v0[2], v0[3]);
            w[2] = cvtpk(v1[0], v1[1]);
            w[3] = cvtpk(v1[2], v1[3]);
        } else if (kq == 1) {
            f32x4 v0 = LOAD16(base4 + 296 * 4);
            w[0] = cvtpk(v0[0], v0[1]);
            w[1] = cvtpk(v0[2], v0[3]);
        }
        a[9] = __builtin_bit_cast(frag_ab, w);
    }
#undef LOAD16

    __syncthreads();                            // Bp ready

    f32x4 acc[5];
    #pragma unroll
    for (int n = 0; n < 5; ++n) acc[n] = (f32x4){0.f, 0.f, 0.f, 0.f};

    #pragma unroll
    for (int kc = 0; kc < 10; ++kc) {
        #pragma unroll
        for (int n = 0; n < 5; ++n) {
            frag_ab b = *(const frag_ab*)&Bp[((kc * 5 + n) * 64 + lane) * 8];
            acc[n] = __builtin_amdgcn_mfma_f32_16x16x32_bf16(a[kc], b, acc[n], 0, 0, 0);
        }
    }

    // Shuffle epilogue. C layout: col = n*16 + (lane&15), row = (lane>>4)*4 + r.
    // re(j) = col j, im(j) = col j+35; single source lane (lane&48)|((c+3)&15).
    const int src = (lane & 48) | ((c16 + 3) & 15);
    #pragma unroll
    for (int r = 0; r < 4; ++r) {
        float re0 = acc[0][r], re1 = acc[1][r], re2 = acc[2][r];
        float sh2 = __shfl(acc[2][r], src);
        float sh3 = __shfl(acc[3][r], src);
        float sh4 = __shfl(acc[4][r], src);
        float im0 = (c16 < 13) ? sh2 : sh3;
        float im1 = (c16 < 13) ? sh3 : sh4;
        float p0 = re0 * re0 + im0 * im0;
        float p1 = re1 * re1 + im1 * im1;
        float p2 = (c16 < 3) ? (re2 * re2 + sh4 * sh4) : 0.0f;
        float ps = p0 + p1 + p2;
        ps += __shfl_xor(ps, 1);
        ps += __shfl_xor(ps, 2);
        ps += __shfl_xor(ps, 4);
        ps += __shfl_xor(ps, 8);
        float inv = 1.0f / ps;
        int row = kq * 4 + r;
        float* orow = out + ((size_t)bc * 16 + row) * 35;
        orow[c16]      = p0 * inv;
        orow[16 + c16] = p1 * inv;
        if (c16 < 3) orow[32 + c16] = p2 * inv;
    }
}

extern "C" void kernel_launch(void* const* d_in, const int* in_sizes, int n_in,
                              void* d_out, int out_size, void* d_ws, size_t ws_size,
                              hipStream_t stream) {
    const float* x    = (const float*)d_in[0];
    const int*   offs = (const int*)d_in[1];
    float*       out  = (float*)d_out;
    // 4096 (b,c) pairs, 8 per block
    hipLaunchKernelGGL(st_spec_main, dim3(512), dim3(512), 0, stream,
                       x, offs, out);
}

// Round 6
// 20.342 us; speedup vs baseline: 1.0101x; 1.0101x over previous
//
#include <hip/hip_runtime.h>
#include <hip/hip_bf16.h>

using frag_ab = __attribute__((ext_vector_type(8))) short;   // 8 bf16 in 4 VGPRs
using f32x4   = __attribute__((ext_vector_type(4))) float;
using i32x4   = __attribute__((ext_vector_type(4))) int;
typedef float f32x4u __attribute__((ext_vector_type(4), aligned(4)));
using u16x8   = __attribute__((ext_vector_type(8))) unsigned short;  // 16 B

#if defined(__has_builtin)
#  if __has_builtin(__builtin_amdgcn_make_buffer_rsrc) && __has_builtin(__builtin_amdgcn_raw_buffer_load_b128)
#    define USE_BUF 1
#  endif
#endif

// ======== compile-time twiddle table ========
// B(320 x 80): col 0..34 = cos(2*pi*(7+j)*k/300), col 35..69 = sin(...), else 0.
// Packed in MFMA fragment order, one chunk per kc:
//   chunk[kc].v[(n*64 + lane)*8 + e],  k = kc*32 + (lane>>4)*8 + e, col = n*16 + (lane&15)

struct CS { double c[300]; double s[300]; };

constexpr CS make_cs() {
    CS t{};
    const double PI = 3.14159265358979323846;
    for (int m = 0; m < 300; ++m) {
        int q = m / 75, r = m % 75;
        double th = PI * (double)r / 150.0;     // [0, pi/2)
        double x2 = th * th;
        double term = 1.0, cv = 0.0;
        for (int k2 = 0; k2 < 12; ++k2) { cv += term; term *= -x2 / ((2*k2+1)*(2*k2+2)); }
        double sv = 0.0; term = th;
        for (int k2 = 0; k2 < 12; ++k2) { sv += term; term *= -x2 / ((2*k2+2)*(2*k2+3)); }
        double cc = 0.0, ss = 0.0;
        if      (q == 0) { cc =  cv; ss =  sv; }
        else if (q == 1) { cc = -sv; ss =  cv; }
        else if (q == 2) { cc = -cv; ss = -sv; }
        else             { cc =  sv; ss = -cv; }
        t.c[m] = cc; t.s[m] = ss;
    }
    return t;
}
constexpr CS TAB = make_cs();

constexpr unsigned short d2bf(double v) {
    unsigned s = 0; double a = v;
    if (a < 0) { s = 1; a = -a; }
    if (a < 1e-8) return 0;                 // exact zeros of the twiddle grid
    int e = 0;
    while (a >= 2.0) { a *= 0.5; ++e; }
    while (a <  1.0) { a *= 2.0; --e; }
    double m = (a - 1.0) * 128.0;           // 7-bit bf16 mantissa
    int mi = (int)(m + 0.5);
    int ef = 127 + e;
    if (mi == 128) { mi = 0; ++ef; }
    return (unsigned short)((s << 15) | ((unsigned)ef << 7) | (unsigned)mi);
}

struct alignas(16) Chunk { unsigned short v[2560]; };   // [n=5][lane=64][e=8]

constexpr Chunk make_chunk(int kc) {
    Chunk ch{};
    for (int i = 0; i < 2560; ++i) {
        int e = i & 7, l = (i >> 3) & 63, n = i >> 9;
        int k   = kc * 32 + ((l >> 4) << 3) + e;
        int col = n * 16 + (l & 15);
        double v = 0.0;
        if (k < 300 && col < 70) {
            int j = (col < 35) ? col : col - 35;
            int m = ((7 + j) * k) % 300;        // exact integer angle index
            v = (col < 35) ? TAB.c[m] : TAB.s[m];
        }
        ch.v[i] = d2bf(v);
    }
    return ch;
}

__device__ constexpr Chunk BPALL[10] = {
    make_chunk(0), make_chunk(1), make_chunk(2), make_chunk(3), make_chunk(4),
    make_chunk(5), make_chunk(6), make_chunk(7), make_chunk(8), make_chunk(9)
};

// 2 f32 -> packed 2x bf16 (low = lo, high = hi), single HW instruction
__device__ __forceinline__ unsigned cvtpk(float lo, float hi) {
    unsigned r;
    asm("v_cvt_pk_bf16_f32 %0, %1, %2" : "=v"(r) : "v"(lo), "v"(hi));
    return r;
}

// 512 threads = 8 waves, one (b,c) pair per wave.
// Order: stage B to LDS -> barrier -> gather A -> MFMA.  The barrier sits
// BEFORE the gather so the compiler's vmcnt(0)-drain at s_barrier only waits
// on the tiny staging loads; the 20 gather loads then overlap the MFMA phase
// via fine-grained per-use vmcnt, and waves are not coupled on gather latency.
__global__ __launch_bounds__(512) void st_spec_main(
    const float* __restrict__ x, const int* __restrict__ offs,
    float* __restrict__ out)
{
    __shared__ __align__(16) unsigned short Bp[25600];   // 51200 B

    const int tid  = threadIdx.x;
    const int wave = tid >> 6;
    const int lane = tid & 63;
    const int bc   = blockIdx.x * 8 + wave;     // 0..4095 (b*32+c)
    const int c16  = lane & 15;                 // A row = window index / C col
    const int kq   = lane >> 4;                 // k-quarter

    // issue the offset load first; it's needed right after the barrier
    const int off = offs[bc * 16 + c16];

    // stage twiddle table: constexpr global -> LDS, 16 B per thread-iter
    {
        const u16x8* src = (const u16x8*)&BPALL[0];
        u16x8* dst = (u16x8*)Bp;
        #pragma unroll
        for (int i = 0; i < 6; ++i) dst[tid + i * 512] = src[tid + i * 512];
        int i6 = tid + 6 * 512;
        if (i6 < 3200) dst[i6] = src[i6];
    }

    __syncthreads();                            // drains only staging, not gather

    const int base4 = (bc * 9000 + off) * 4;    // byte offset of window start

#ifdef USE_BUF
    __amdgpu_buffer_rsrc_t rsrc = __builtin_amdgcn_make_buffer_rsrc(
        (void*)x, (short)0, 128 * 32 * 9000 * 4, 0x00020000);
#   define LOAD16(bo) __builtin_bit_cast(f32x4, __builtin_amdgcn_raw_buffer_load_b128(rsrc, (bo), 0, 0))
#else
#   define LOAD16(bo) (*(const f32x4u*)((const char*)x + (bo)))
#endif

    // A fragments straight from global (runtime offsets), zero-pad t>=300
    frag_ab a[10];
    #pragma unroll
    for (int kc = 0; kc < 9; ++kc) {           // t <= 295 < 300, safe
        int bo = base4 + (kc * 32 + kq * 8) * 4;
        f32x4 v0 = LOAD16(bo);
        f32x4 v1 = LOAD16(bo + 16);
        i32x4 w;
        w[0] = cvtpk(v0[0], v0[1]);
        w[1] = cvtpk(v0[2], v0[3]);
        w[2] = cvtpk(v1[0], v1[1]);
        w[3] = cvtpk(v1[2], v1[3]);
        a[kc] = __builtin_bit_cast(frag_ab, w);
    }
    {
        // tail k-chunk: kq=0 -> t 288..295, kq=1 -> t 296..299 valid, else zero
        i32x4 w = (i32x4){0, 0, 0, 0};
        if (kq == 0) {
            f32x4 v0 = LOAD16(base4 + 288 * 4);
            f32x4 v1 = LOAD16(base4 + 292 * 4);
            w[0] = cvtpk(v0[0], v0[1]);
            w[1] = cvtpk(v0[2], v0[3]);
            w[2] = cvtpk(v1[0], v1[1]);
            w[3] = cvtpk(v1[2], v1[3]);
        } else if (kq == 1) {
            f32x4 v0 = LOAD16(base4 + 296 * 4);
            w[0] = cvtpk(v0[0], v0[1]);
            w[1] = cvtpk(v0[2], v0[3]);
        }
        a[9] = __builtin_bit_cast(frag_ab, w);
    }
#undef LOAD16

    f32x4 acc[5];
    #pragma unroll
    for (int n = 0; n < 5; ++n) acc[n] = (f32x4){0.f, 0.f, 0.f, 0.f};

    #pragma unroll
    for (int kc = 0; kc < 10; ++kc) {
        #pragma unroll
        for (int n = 0; n < 5; ++n) {
            frag_ab b = *(const frag_ab*)&Bp[((kc * 5 + n) * 64 + lane) * 8];
            acc[n] = __builtin_amdgcn_mfma_f32_16x16x32_bf16(a[kc], b, acc[n], 0, 0, 0);
        }
    }

    // Shuffle epilogue. C layout: col = n*16 + (lane&15), row = (lane>>4)*4 + r.
    // re(j) = col j, im(j) = col j+35; single source lane (lane&48)|((c+3)&15).
    const int src = (lane & 48) | ((c16 + 3) & 15);
    #pragma unroll
    for (int r = 0; r < 4; ++r) {
        float re0 = acc[0][r], re1 = acc[1][r], re2 = acc[2][r];
        float sh2 = __shfl(acc[2][r], src);
        float sh3 = __shfl(acc[3][r], src);
        float sh4 = __shfl(acc[4][r], src);
        float im0 = (c16 < 13) ? sh2 : sh3;
        float im1 = (c16 < 13) ? sh3 : sh4;
        float p0 = re0 * re0 + im0 * im0;
        float p1 = re1 * re1 + im1 * im1;
        float p2 = (c16 < 3) ? (re2 * re2 + sh4 * sh4) : 0.0f;
        float ps = p0 + p1 + p2;
        ps += __shfl_xor(ps, 1);
        ps += __shfl_xor(ps, 2);
        ps += __shfl_xor(ps, 4);
        ps += __shfl_xor(ps, 8);
        float inv = 1.0f / ps;
        int row = kq * 4 + r;
        float* orow = out + ((size_t)bc * 16 + row) * 35;
        orow[c16]      = p0 * inv;
        orow[16 + c16] = p1 * inv;
        if (c16 < 3) orow[32 + c16] = p2 * inv;
    }
}

extern "C" void kernel_launch(void* const* d_in, const int* in_sizes, int n_in,
                              void* d_out, int out_size, void* d_ws, size_t ws_size,
                              hipStream_t stream) {
    const float* x    = (const float*)d_in[0];
    const int*   offs = (const int*)d_in[1];
    float*       out  = (float*)d_out;
    // 4096 (b,c) pairs, 8 per block
    hipLaunchKernelGGL(st_spec_main, dim3(512), dim3(512), 0, stream,
                       x, offs, out);
}